// Round 1
// 1091.677 us; speedup vs baseline: 1.0278x; 1.0278x over previous
//
#include <hip/hip_runtime.h>
#include <hip/hip_bf16.h>

// Multi-LoRA fused: out[b,n,o] = (1/64) * sum_r ( sum_i x[b,n,i]*B[aid,r,i] ) * A[aid,o,r]
// x: [16,2048,4096] f32, ids: [16] int32, A: [64,4096,64] f32, B: [64,64,4096] f32
// out: [16,2048,4096] f32
//
// R1 changes vs 1122us baseline (latency-bound: Occ 21%, MfmaUtil 3%, HBM 31%):
//  - TN 64->32: grid 512->1024 blocks, 4 blocks/CU co-resident (16 waves/CU).
//  - Stage 1: double-buffered LDS + register prefetch; ONE raw barrier per K-step
//    (asm "s_waitcnt lgkmcnt(0); s_barrier") so prefetch global loads stay in
//    flight across the barrier (no compiler vmcnt(0) drain).
//  - Epilogue stores: plain (not nontemporal) — A/B test for the 736MB vs 536MB
//    WRITE_SIZE amplification.

typedef __bf16 bf16x8 __attribute__((ext_vector_type(8)));
typedef float  f32x4  __attribute__((ext_vector_type(4)));

#define SEQLEN  2048
#define D_IN    4096
#define D_OUT   4096
#define RNK     64
#define TN      32     // rows (n) per block
#define BK      128    // K chunk staged in LDS
#define NKB     (D_IN / BK)  // 32
#define BKP     136    // padded LDS row (bf16 elems): stride 272B
#define BXP     72     // padded Bx LDS row: stride 144B

__device__ __forceinline__ bf16x8 cvt8(f32x4 a, f32x4 b) {
    bf16x8 r;
    r[0] = (__bf16)a[0]; r[1] = (__bf16)a[1]; r[2] = (__bf16)a[2]; r[3] = (__bf16)a[3];
    r[4] = (__bf16)b[0]; r[5] = (__bf16)b[1]; r[6] = (__bf16)b[2]; r[7] = (__bf16)b[3];
    return r;
}

__global__ __launch_bounds__(256, 4) void lora_fused(
    const float* __restrict__ x, const int* __restrict__ ids,
    const float* __restrict__ A, const float* __restrict__ Bw,
    float* __restrict__ out)
{
    __shared__ __bf16 xs[2][TN * BKP];  // 2 x 8704 B
    __shared__ __bf16 bxs[TN * BXP];    // 4608 B  (total 22016 B -> 4+ blocks/CU)

    const int tid  = threadIdx.x;
    const int wave = tid >> 6;
    const int lane = tid & 63;
    const int l15  = lane & 15;
    const int quad = lane >> 4;

    // XCD swizzle: assume round-robin blockIdx->XCD (%8). 128 blocks/XCD =
    // 2 batches/XCD so that XCD's A/B (4 MiB) stay L2-resident.
    const int blk  = blockIdx.x;          // 0..1023
    const int slot = blk >> 3;            // 0..127
    const int b    = (blk & 7) * 2 + (slot >> 6);  // 0..15
    const int nt   = slot & 63;           // 0..63

    const int aid = ids[b];
    const float* xb = x   + ((size_t)b * SEQLEN + (size_t)nt * TN) * D_IN;
    float*       ob = out + ((size_t)b * SEQLEN + (size_t)nt * TN) * D_OUT;
    const float* Aq = A  + (size_t)aid * D_OUT * RNK;
    const float* Bq = Bw + (size_t)aid * RNK * D_IN;

    f32x4 zero; zero[0] = zero[1] = zero[2] = zero[3] = 0.0f;

    // ---- Stage 1: Bx[n, r] = sum_k x[n,k] * B[r,k]; wave w owns r-tile w ----
    f32x4 acc[2];   // 2 n-tiles of 16; lane: row=quad*4+j, col(r)=16w+l15
    acc[0] = zero; acc[1] = zero;

    const int srow = tid >> 3;   // 0..31: staging row
    const int sq   = tid & 7;    // 16-float slice of the 128-wide K chunk
    const float* xsrc = xb + (size_t)srow * D_IN + sq * 16;
    const float* bsrc = Bq + (size_t)(wave * 16 + l15) * D_IN + quad * 8;

    // Prologue: load + stage chunk 0 into xs[0]
    f32x4 pre[4];
    {
        #pragma unroll
        for (int i = 0; i < 4; ++i)
            pre[i] = __builtin_nontemporal_load((const f32x4*)(xsrc + i * 4));
        __bf16* xd = &xs[0][srow * BKP + sq * 16];
        *(bf16x8*)xd       = cvt8(pre[0], pre[1]);
        *(bf16x8*)(xd + 8) = cvt8(pre[2], pre[3]);
    }

    for (int kb = 0; kb < NKB; ++kb) {
        // Issue next chunk's global loads BEFORE the barrier; they stay in
        // flight across it (barrier below waits lgkmcnt only, not vmcnt).
        if (kb + 1 < NKB) {
            const float* sp = xsrc + (size_t)(kb + 1) * BK;
            #pragma unroll
            for (int i = 0; i < 4; ++i)
                pre[i] = __builtin_nontemporal_load((const f32x4*)(sp + i * 4));
        }
        // Raw barrier: drain my LDS ops (writes of xs[kb&1] from prev iter,
        // frag reads of prev iter), then sync. NOT vmcnt(0).
        asm volatile("s_waitcnt lgkmcnt(0)\n\ts_barrier" ::: "memory");

        const float* bp = bsrc + (size_t)kb * BK;
        const __bf16* xc = xs[kb & 1];
        #pragma unroll
        for (int s = 0; s < 4; ++s) {
            f32x4 b0 = *(const f32x4*)(bp + s * 32);
            f32x4 b1 = *(const f32x4*)(bp + s * 32 + 4);
            bf16x8 bfrag = cvt8(b0, b1);  // B[k=quad*8+j][r=16w+l15]
            #pragma unroll
            for (int t = 0; t < 2; ++t) {
                bf16x8 afrag = *(const bf16x8*)&xc[(t * 16 + l15) * BKP + s * 32 + quad * 8];
                acc[t] = __builtin_amdgcn_mfma_f32_16x16x32_bf16(afrag, bfrag, acc[t], 0, 0, 0);
            }
        }

        // Write next chunk to the other buffer (its readers finished before
        // the barrier above; compiler inserts vmcnt wait for pre[] here).
        if (kb + 1 < NKB) {
            __bf16* xd = &xs[(kb + 1) & 1][srow * BKP + sq * 16];
            *(bf16x8*)xd       = cvt8(pre[0], pre[1]);
            *(bf16x8*)(xd + 8) = cvt8(pre[2], pre[3]);
        }
    }

    // ---- Bx -> LDS as bf16 (fold exact 1/64 scaling) ----
    #pragma unroll
    for (int t = 0; t < 2; ++t)
        #pragma unroll
        for (int j = 0; j < 4; ++j)
            bxs[(t * 16 + quad * 4 + j) * BXP + wave * 16 + l15] =
                (__bf16)(acc[t][j] * 0.015625f);
    __syncthreads();

    bf16x8 a2[2][2];  // a2[t][s] = Bx[n=16t+l15][r=s*32+quad*8+j]
    #pragma unroll
    for (int t = 0; t < 2; ++t)
        #pragma unroll
        for (int s = 0; s < 2; ++s)
            a2[t][s] = *(const bf16x8*)&bxs[(t * 16 + l15) * BXP + s * 32 + quad * 8];

    // ---- Stage 2: out[n, o] = sum_r Bx[n,r] * A[o,r]; wave w owns o%256 slice ----
    // No barriers in this loop: waves drift freely, TLP hides A-load + store latency.
    for (int oc = 0; oc < 16; ++oc) {
        const int o0 = oc * 256 + wave * 64;
        bf16x8 b2[4][2];  // lane holds A[o=o0+16ot+l15][r=s*32+quad*8+j]
        #pragma unroll
        for (int ot = 0; ot < 4; ++ot) {
            const float* ap = Aq + (size_t)(o0 + ot * 16 + l15) * RNK + quad * 8;
            #pragma unroll
            for (int s = 0; s < 2; ++s) {
                f32x4 a0 = *(const f32x4*)(ap + s * 32);
                f32x4 a1 = *(const f32x4*)(ap + s * 32 + 4);
                b2[ot][s] = cvt8(a0, a1);
            }
        }
        f32x4 acc2[2][4];
        #pragma unroll
        for (int t = 0; t < 2; ++t)
            #pragma unroll
            for (int ot = 0; ot < 4; ++ot)
                acc2[t][ot] = zero;
        #pragma unroll
        for (int s = 0; s < 2; ++s)
            #pragma unroll
            for (int ot = 0; ot < 4; ++ot)
                #pragma unroll
                for (int t = 0; t < 2; ++t)
                    acc2[t][ot] = __builtin_amdgcn_mfma_f32_16x16x32_bf16(
                        a2[t][s], b2[ot][s], acc2[t][ot], 0, 0, 0);
        // Plain stores (let L2 merge the 64B segments into full lines).
        #pragma unroll
        for (int t = 0; t < 2; ++t)
            #pragma unroll
            for (int j = 0; j < 4; ++j)
                #pragma unroll
                for (int ot = 0; ot < 4; ++ot)
                    ob[(size_t)(t * 16 + quad * 4 + j) * D_OUT + o0 + ot * 16 + l15] =
                        acc2[t][ot][j];
    }
}

extern "C" void kernel_launch(void* const* d_in, const int* in_sizes, int n_in,
                              void* d_out, int out_size, void* d_ws, size_t ws_size,
                              hipStream_t stream) {
    (void)in_sizes; (void)n_in; (void)d_ws; (void)ws_size; (void)out_size;
    const float* x   = (const float*)d_in[0];
    const int*   ids = (const int*)d_in[1];
    const float* A   = (const float*)d_in[2];
    const float* B   = (const float*)d_in[3];
    float*       out = (float*)d_out;

    dim3 grid(1024), block(256);
    hipLaunchKernelGGL(lora_fused, grid, block, 0, stream, x, ids, A, B, out);
}